// Round 1
// baseline (142.784 us; speedup 1.0000x reference)
//
#include <hip/hip_runtime.h>
#include <hip/hip_bf16.h>
#include <cstdint>
#include <cstddef>

#define NROWS 16384
#define DDIM  256
#define SPLITS 16                  // 128 row-blocks x 16 col-splits = 2048 blocks
#define NTILES 256                 // 16384 cols / 64
#define TILES_PER (NTILES / SPLITS)

typedef __attribute__((ext_vector_type(4))) float f32x4;
typedef __attribute__((ext_vector_type(4))) float fl4;
typedef __attribute__((ext_vector_type(4))) int   i32x4;
typedef __attribute__((ext_vector_type(8))) int   i32x8;

constexpr float SCALE_EXP2 = 20.609929155556627f; // log2(e)/0.07 folded into qn
constexpr float LN2F       = 0.69314718055994531f;
constexpr float INV_T      = 14.285714285714286f;

__device__ inline void gload_lds16(const void* g, void* l) {
  __builtin_amdgcn_global_load_lds(
      (const __attribute__((address_space(1))) void*)g,
      (__attribute__((address_space(3))) void*)l, 16, 0, 0);
}

// ---- kernel 1: one wave per row i: normalize q_i,k_i -> fp8 (q side pre-scaled
// by log2(e)/T), fp32 diag_i, zero rowsum. No LDS, no barriers.
__global__ __launch_bounds__(256) void norm_kernel(
    const float* __restrict__ q, const float* __restrict__ k,
    unsigned char* __restrict__ qn, unsigned char* __restrict__ kn,
    float* __restrict__ diag, float* __restrict__ rowsum,
    float* __restrict__ out)
{
  const int wave = threadIdx.x >> 6, lane = threadIdx.x & 63;
  const int row = blockIdx.x * 4 + wave;
  const size_t off = (size_t)row * DDIM + lane * 4;

  fl4 vq = *(const fl4*)(q + off);
  fl4 vk = *(const fl4*)(k + off);
  float ssq = vq.x * vq.x + vq.y * vq.y + vq.z * vq.z + vq.w * vq.w;
  float ssk = vk.x * vk.x + vk.y * vk.y + vk.z * vk.z + vk.w * vk.w;
  float dot = vq.x * vk.x + vq.y * vk.y + vq.z * vk.z + vq.w * vk.w;
#pragma unroll
  for (int m = 1; m < 64; m <<= 1) {
    ssq += __shfl_xor(ssq, m, 64);
    ssk += __shfl_xor(ssk, m, 64);
    dot += __shfl_xor(dot, m, 64);
  }
  float rq = 1.0f / fmaxf(sqrtf(ssq), 1e-12f);
  float rk = 1.0f / fmaxf(sqrtf(ssk), 1e-12f);

  float sq = rq * SCALE_EXP2;   // fold exp2 scale into q side
  int pq = __builtin_amdgcn_cvt_pk_fp8_f32(vq.x * sq, vq.y * sq, 0, false);
  pq     = __builtin_amdgcn_cvt_pk_fp8_f32(vq.z * sq, vq.w * sq, pq, true);
  *(int*)(qn + off) = pq;
  int pk = __builtin_amdgcn_cvt_pk_fp8_f32(vk.x * rk, vk.y * rk, 0, false);
  pk     = __builtin_amdgcn_cvt_pk_fp8_f32(vk.z * rk, vk.w * rk, pk, true);
  *(int*)(kn + off) = pk;

  if (lane == 0) {
    diag[row]   = dot * rq * rk * INV_T;
    rowsum[row] = 0.0f;
    if (row == 0) out[0] = 0.0f;
  }
}

// ---- kernel 2 (v2): 128-row blocks (4 waves x 32 rows), deferred-epilogue
// software pipeline. Per cs: issue ds_reads -> exp2/sum epilogue of PREVIOUS
// cs (covers LDS latency) -> MFMAs of current cs. Acc ping-pong (E/O) makes
// this branchless; accO seeded with -1e30 so the first epilogue adds exp2(-inf)=0.
// Halved per-wave rows (A-hoard 32 VGPRs) keeps total ~110 VGPRs -> 4 waves/SIMD.
// CRITICAL (R6 NaN post-mortem): compiler does NOT drain LDS-DMA before
// s_barrier -- explicit vmcnt(0) wait (0x0F70: expcnt/lgkmcnt masked off)
// before __syncthreads() is required.
// __launch_bounds__(256) ONLY -- any min-waves arg splits the unified file and
// spills the A-hoard (R4/R5: 133MB-1GB scratch traffic).
__global__ __launch_bounds__(256) void lse_kernel(
    const unsigned char* __restrict__ qn, const unsigned char* __restrict__ kn,
    float* __restrict__ rowsum)
{
  __shared__ __attribute__((aligned(16))) unsigned char Bs[2][64 * DDIM]; // 2 x 16 KB

  const int tid  = threadIdx.x;
  const int wave = tid >> 6, lane = tid & 63;
  const int l15  = lane & 15, quad = lane >> 4;
  const int split = blockIdx.x % SPLITS;
  const int rb    = blockIdx.x / SPLITS;
  const int wrow  = rb * 128 + wave * 32;
  const int t0 = split * TILES_PER;
  const int t1 = t0 + TILES_PER;

  // Staging addresses (i-invariant): chunk L = i*256+tid -> row n = i*16+Ln,
  // slot jj = tid&15 holds global chunk j = jj ^ (n&15) = Ljj ^ Ln.
  const int Ln = tid >> 4, Ljj = tid & 15;
  const int Lj = Ljj ^ Ln;
  const size_t src_off = (size_t)Ln * DDIM + (size_t)Lj * 16;

  // A fragments: 2 subtiles x 2 K-steps(128) x 32B/lane = 32 VGPRs.
  // Layout (16x16x128 f8f6f4): m = lane&15, k = quad*32 + j.
  i32x8 A00, A01, A10, A11;
  {
    const unsigned char* ap0 = qn + (size_t)(wrow + l15) * DDIM + quad * 32;
    const unsigned char* ap1 = qn + (size_t)(wrow + 16 + l15) * DDIM + quad * 32;
    A00 = *(const i32x8*)(ap0);
    A01 = *(const i32x8*)(ap0 + 128);
    A10 = *(const i32x8*)(ap1);
    A11 = *(const i32x8*)(ap1 + 128);
  }

  // Per-lane swizzled LDS read offsets. n = cs*16+l15 so n&15 == l15 for all
  // cs: the XOR slot pattern is cs-invariant, only +cs*4096 changes.
  const int rowoff = l15 * DDIM;
  const int c0  = quad * 2;
  const int o00 = rowoff + (((c0    ) ^ l15) * 16);
  const int o01 = rowoff + (((c0 + 1) ^ l15) * 16);
  const int o10 = rowoff + (((c0 + 8) ^ l15) * 16);
  const int o11 = rowoff + (((c0 + 9) ^ l15) * 16);

  f32x4 sums0 = {0.f, 0.f, 0.f, 0.f}, sums1 = {0.f, 0.f, 0.f, 0.f};
  f32x4 accE0, accE1, accO0, accO1;
  accO0 = (f32x4){-1e30f, -1e30f, -1e30f, -1e30f};  // exp2 -> 0 on first epilogue
  accO1 = accO0;

  // prefetch first tile into buffer 0
  {
    const unsigned char* kbase = kn + (size_t)t0 * (64 * DDIM) + src_off;
#pragma unroll
    for (int i = 0; i < 4; ++i)
      gload_lds16(kbase + i * 4096, (void*)(Bs[0] + tid * 16 + i * 4096));
  }

#define EPI(P0, P1) do {                                                      \
    f32x4 e0_, e1_;                                                           \
    e0_[0] = __builtin_amdgcn_exp2f(P0[0]);                                   \
    e0_[1] = __builtin_amdgcn_exp2f(P0[1]);                                   \
    e0_[2] = __builtin_amdgcn_exp2f(P0[2]);                                   \
    e0_[3] = __builtin_amdgcn_exp2f(P0[3]);                                   \
    e1_[0] = __builtin_amdgcn_exp2f(P1[0]);                                   \
    e1_[1] = __builtin_amdgcn_exp2f(P1[1]);                                   \
    e1_[2] = __builtin_amdgcn_exp2f(P1[2]);                                   \
    e1_[3] = __builtin_amdgcn_exp2f(P1[3]);                                   \
    sums0 += e0_;                                                             \
    sums1 += e1_;                                                             \
  } while (0)

#define CS_STEP(C0, C1, P0, P1, BOFF) do {                                    \
    i32x4 lo0_ = *(const i32x4*)(bb + (BOFF) + o00);                          \
    i32x4 hi0_ = *(const i32x4*)(bb + (BOFF) + o01);                          \
    i32x4 lo1_ = *(const i32x4*)(bb + (BOFF) + o10);                          \
    i32x4 hi1_ = *(const i32x4*)(bb + (BOFF) + o11);                          \
    EPI(P0, P1); /* exp2 of previous cs while ds_reads fly */                 \
    i32x8 b0_ = {lo0_.x, lo0_.y, lo0_.z, lo0_.w, hi0_.x, hi0_.y, hi0_.z, hi0_.w}; \
    i32x8 b1_ = {lo1_.x, lo1_.y, lo1_.z, lo1_.w, hi1_.x, hi1_.y, hi1_.z, hi1_.w}; \
    __builtin_amdgcn_s_setprio(1);                                            \
    C0 = __builtin_amdgcn_mfma_scale_f32_16x16x128_f8f6f4(                    \
        A00, b0_, (f32x4){0.f, 0.f, 0.f, 0.f}, 0, 0, 0, 127, 0, 127);         \
    C1 = __builtin_amdgcn_mfma_scale_f32_16x16x128_f8f6f4(                    \
        A10, b0_, (f32x4){0.f, 0.f, 0.f, 0.f}, 0, 0, 0, 127, 0, 127);         \
    C0 = __builtin_amdgcn_mfma_scale_f32_16x16x128_f8f6f4(                    \
        A01, b1_, C0, 0, 0, 0, 127, 0, 127);                                  \
    C1 = __builtin_amdgcn_mfma_scale_f32_16x16x128_f8f6f4(                    \
        A11, b1_, C1, 0, 0, 0, 127, 0, 127);                                  \
    __builtin_amdgcn_s_setprio(0);                                            \
  } while (0)

  for (int ct = t0; ct < t1; ++ct) {
    const int cur = (ct - t0) & 1;
    __builtin_amdgcn_s_waitcnt(0x0F70);  // vmcnt(0) only: drain buf[cur]'s LDS-DMA
    __syncthreads();                     // + all waves done reading buf[cur^1]
    if (ct + 1 < t1) {
      const unsigned char* kbase = kn + (size_t)(ct + 1) * (64 * DDIM) + src_off;
#pragma unroll
      for (int i = 0; i < 4; ++i)
        gload_lds16(kbase + i * 4096, (void*)(Bs[cur ^ 1] + tid * 16 + i * 4096));
    }
    const unsigned char* bb = Bs[cur];
    // parity ping-pong: even cs -> accE (epilogue accO), odd cs -> accO (epilogue accE)
    CS_STEP(accE0, accE1, accO0, accO1, 0);
    CS_STEP(accO0, accO1, accE0, accE1, 4096);
    CS_STEP(accE0, accE1, accO0, accO1, 8192);
    CS_STEP(accO0, accO1, accE0, accE1, 12288);
  }
  EPI(accO0, accO1);  // drain the final pending accumulator

#undef CS_STEP
#undef EPI

  // C/D: col = lane&15 (the 16 kn columns), row = quad*4 + r. Reduce over l15.
#pragma unroll
  for (int r = 0; r < 4; ++r) {
    float v0 = sums0[r], v1 = sums1[r];
    v0 += __shfl_xor(v0, 1, 64);  v1 += __shfl_xor(v1, 1, 64);
    v0 += __shfl_xor(v0, 2, 64);  v1 += __shfl_xor(v1, 2, 64);
    v0 += __shfl_xor(v0, 4, 64);  v1 += __shfl_xor(v1, 4, 64);
    v0 += __shfl_xor(v0, 8, 64);  v1 += __shfl_xor(v1, 8, 64);
    if (l15 == 0) {
      atomicAdd(&rowsum[wrow + quad * 4 + r], v0);
      atomicAdd(&rowsum[wrow + 16 + quad * 4 + r], v1);
    }
  }
}

// ---- kernel 3: out = mean(ln(rowsum) - diag)
__global__ void final_kernel(const float* __restrict__ rowsum,
                             const float* __restrict__ diag,
                             float* __restrict__ out)
{
  int row = blockIdx.x * 256 + threadIdx.x;
  float c = __builtin_amdgcn_logf(rowsum[row]) * LN2F - diag[row];
#pragma unroll
  for (int m = 1; m < 64; m <<= 1) c += __shfl_xor(c, m, 64);
  __shared__ float red[4];
  int wave = threadIdx.x >> 6, lane = threadIdx.x & 63;
  if (lane == 0) red[wave] = c;
  __syncthreads();
  if (threadIdx.x == 0) {
    float s = red[0] + red[1] + red[2] + red[3];
    atomicAdd(out, s * (1.0f / NROWS));
  }
}

extern "C" void kernel_launch(void* const* d_in, const int* in_sizes, int n_in,
                              void* d_out, int out_size, void* d_ws, size_t ws_size,
                              hipStream_t stream)
{
  const float* q = (const float*)d_in[0];
  const float* k = (const float*)d_in[1];
  float* out = (float*)d_out;

  char* ws = (char*)d_ws;
  unsigned char* qn = (unsigned char*)ws;                    // 4 MB
  unsigned char* kn = (unsigned char*)(ws + (4u << 20));     // 4 MB
  float* diag   = (float*)(ws + (8u << 20));                 // 64 KB
  float* rowsum = (float*)(ws + (8u << 20) + (64u << 10));   // 64 KB

  norm_kernel <<<NROWS / 4, 256, 0, stream>>>(q, k, qn, kn, diag, rowsum, out);
  lse_kernel  <<<(NROWS / 128) * SPLITS, 256, 0, stream>>>(qn, kn, rowsum);
  final_kernel<<<NROWS / 256, 256, 0, stream>>>(rowsum, diag, out);
}